// Round 5
// baseline (45.496 us; speedup 1.0000x reference)
//
#include <hip/hip_runtime.h>

// CubeLens: radial lens deflection + bilinear gather + 4x4 avg pool.
// C=64, NS=256, NL=192, UPS=4. Output (64,192,192) fp32.
//
// R5 = R4 with the nontemporal builtins fixed (native clang vector type;
// HIP's float4 is a struct and is rejected by __builtin_nontemporal_*).
//
//   k1: transpose src (64,256,256) -> ws (256,256,64), float4 both sides,
//       nontemporal src reads.
//   k2: block = 32 output pixels x 64 channels; 16-lane group owns 2 pixels.
//       - geometry: lane = tap (4x4 upsample grid), 2 pixels per lane
//       - footprint min/max via 4 shfl_xor butterflies (16-lane groups)
//       - per-corner weights: 4 LDS atomicAdd per in-bounds tap
//       - gather: BRANCHLESS. All 16 corners loaded unconditionally,
//         2 px interleaved -> 16 independent loads in flight.
//       - fallback per-tap path for wide-span pixels (group-uniform).
//       - output via LDS repack -> nontemporal float4 stores.
//       - XCD swizzle: blockIdx%8 -> contiguous band per XCD.

#define NSRC 256
#define NLENS 192
#define NPIX (NLENS * NLENS)     // 36864
#define CSZ  64
#define PXB  32                  // pixels per block
#define NBLK (NPIX / PXB)        // 1152, divisible by 8

typedef float f32x4 __attribute__((ext_vector_type(4)));

// ---------------- fallback (round-1 kernel, used only if ws too small) ------
__global__ __launch_bounds__(256) void cubelens_fallback(
    const float* __restrict__ src, const float* __restrict__ theta_p,
    float* __restrict__ out)
{
    const float tE = theta_p[0];
    const int pix = blockIdx.x * 256 + threadIdx.x;
    const int c0  = blockIdx.y * 8;
    const int lx  = pix % NLENS;
    const int ly  = pix / NLENS;
    float acc[8];
#pragma unroll
    for (int c = 0; c < 8; ++c) acc[c] = 0.0f;
    const float* __restrict__ srcg = src + (size_t)c0 * (NSRC * NSRC);
#pragma unroll
    for (int uy = 0; uy < 4; ++uy) {
        const float thy = ((float)(ly * 4 + uy) - 383.5f) * 0.01f;
#pragma unroll
        for (int ux = 0; ux < 4; ++ux) {
            const float thx = ((float)(lx * 4 + ux) - 383.5f) * 0.01f;
            const float r  = sqrtf(thx * thx + thy * thy) + 1e-8f;
            const float fx = (thx - (tE * thx) / r) / 0.02f + 127.5f;
            const float fy = (thy - (tE * thy) / r) / 0.02f + 127.5f;
            const bool inb = (fx >= 0.0f) & (fx <= 255.0f) &
                             (fy >= 0.0f) & (fy <= 255.0f);
            if (!inb) continue;
            int x0 = min(max((int)floorf(fx), 0), 254);
            int y0 = min(max((int)floorf(fy), 0), 254);
            const float wx = fminf(fmaxf(fx - (float)x0, 0.0f), 1.0f);
            const float wy = fminf(fmaxf(fy - (float)y0, 0.0f), 1.0f);
            const float w00 = (1.0f - wy) * (1.0f - wx);
            const float w01 = (1.0f - wy) * wx;
            const float w10 = wy * (1.0f - wx);
            const float w11 = wy * wx;
            const float* __restrict__ p = srcg + y0 * NSRC + x0;
#pragma unroll
            for (int c = 0; c < 8; ++c) {
                const float* __restrict__ pc = p + c * (NSRC * NSRC);
                acc[c] += w00 * pc[0] + w01 * pc[1]
                        + w10 * pc[NSRC] + w11 * pc[NSRC + 1];
            }
        }
    }
#pragma unroll
    for (int c = 0; c < 8; ++c)
        out[(size_t)(c0 + c) * NPIX + pix] = acc[c] * 0.0625f;
}

// ---------------- k1: transpose (c, p) -> (p, c), float4 both sides ---------
__global__ __launch_bounds__(256) void transpose_kernel(
    const float* __restrict__ src, float* __restrict__ ws)
{
    __shared__ float tile[CSZ][65];
    const int p0 = blockIdx.x * 64;
    const int t  = threadIdx.x;
    {
        const int crow = t >> 4;            // 0..15
        const int px4  = (t & 15) * 4;      // 0..60
#pragma unroll
        for (int i = 0; i < 4; ++i) {
            const int c = crow + 16 * i;
            const f32x4 v = __builtin_nontemporal_load(
                (const f32x4*)(src + (size_t)c * (NSRC * NSRC) + p0 + px4));
            tile[c][px4 + 0] = v.x; tile[c][px4 + 1] = v.y;
            tile[c][px4 + 2] = v.z; tile[c][px4 + 3] = v.w;
        }
    }
    __syncthreads();
    {
        const int prow = t >> 4;            // 0..15
        const int c4   = (t & 15) * 4;      // 0..60
#pragma unroll
        for (int i = 0; i < 4; ++i) {
            const int p = prow + 16 * i;
            f32x4 v;
            v.x = tile[c4 + 0][p]; v.y = tile[c4 + 1][p];
            v.z = tile[c4 + 2][p]; v.w = tile[c4 + 3][p];
            *(f32x4*)(ws + (size_t)(p0 + p) * CSZ + c4) = v;
        }
    }
}

// ---------------- k2: lens gather, branchless patch gather ------------------
struct Tap { int x0, y0; float wx, wy; bool inb; };

__device__ __forceinline__ Tap tapgeom(int p, int sub, float tE) {
    const int lx = p % NLENS, ly = p / NLENS;
    const float thy = ((float)(ly * 4 + (sub >> 2)) - 383.5f) * 0.01f;
    const float thx = ((float)(lx * 4 + (sub & 3))  - 383.5f) * 0.01f;
    const float r  = sqrtf(thx * thx + thy * thy) + 1e-8f;
    const float fx = (thx - (tE * thx) / r) / 0.02f + 127.5f;
    const float fy = (thy - (tE * thy) / r) / 0.02f + 127.5f;
    Tap tp;
    tp.inb = (fx >= 0.0f) & (fx <= 255.0f) & (fy >= 0.0f) & (fy <= 255.0f);
    tp.x0 = min(max((int)floorf(fx), 0), 254);
    tp.y0 = min(max((int)floorf(fy), 0), 254);
    tp.wx = fminf(fmaxf(fx - (float)tp.x0, 0.0f), 1.0f);
    tp.wy = fminf(fmaxf(fy - (float)tp.y0, 0.0f), 1.0f);
    return tp;
}

__device__ __forceinline__ void footprint(const Tap& tp, int& bx0, int& by0,
                                          bool& pm) {
    int mnx = tp.inb ? tp.x0 :  0x0FFFFFFF;
    int mny = tp.inb ? tp.y0 :  0x0FFFFFFF;
    int mxx = tp.inb ? tp.x0 : -0x0FFFFFFF;
    int mxy = tp.inb ? tp.y0 : -0x0FFFFFFF;
#pragma unroll
    for (int off = 1; off < 16; off <<= 1) {
        mnx = min(mnx, __shfl_xor(mnx, off, 16));
        mny = min(mny, __shfl_xor(mny, off, 16));
        mxx = max(mxx, __shfl_xor(mxx, off, 16));
        mxy = max(mxy, __shfl_xor(mxy, off, 16));
    }
    pm = (mxx - mnx <= 2) && (mxy - mny <= 2);
    bx0 = max(min(mnx, 252), 0);
    by0 = max(min(mny, 252), 0);
}

__device__ __forceinline__ f32x4 tap_fallback(const float* __restrict__ ws,
                                              const Tap& tp, int c4o) {
    f32x4 acc = {0.f, 0.f, 0.f, 0.f};
    for (int j = 0; j < 16; ++j) {
        const int   tx0 = __shfl(tp.x0, j, 16);
        const int   ty0 = __shfl(tp.y0, j, 16);
        const float twx = __shfl(tp.wx, j, 16);
        const float twy = __shfl(tp.wy, j, 16);
        const int   tin = __shfl((int)tp.inb, j, 16);
        if (tin) {
            const float* __restrict__ pp =
                ws + (size_t)(ty0 * NSRC + tx0) * CSZ + c4o;
            const f32x4 v00 = *(const f32x4*)(pp);
            const f32x4 v01 = *(const f32x4*)(pp + CSZ);
            const f32x4 v10 = *(const f32x4*)(pp + NSRC * CSZ);
            const f32x4 v11 = *(const f32x4*)(pp + NSRC * CSZ + CSZ);
            const float w00 = (1.0f - twy) * (1.0f - twx);
            const float w01 = (1.0f - twy) * twx;
            const float w10 = twy * (1.0f - twx);
            const float w11 = twy * twx;
            acc += w00 * v00 + w01 * v01 + w10 * v10 + w11 * v11;
        }
    }
    return acc;
}

__global__ __launch_bounds__(256) void cubelens_main(
    const float* __restrict__ ws,       // (256,256,64)
    const float* __restrict__ theta_p,
    float* __restrict__ out)            // (64,192,192)
{
    __shared__ float wpatch[PXB][16];       // per-pixel 4x4 corner weights
    __shared__ int   gbase[PXB];
    __shared__ int   gmode[PXB];
    __shared__ float smemO[CSZ][PXB + 1];

    const float tE = theta_p[0];
    const int b = blockIdx.x;
    const int pixblock = (b & 7) * (NBLK / 8) + (b >> 3);   // XCD swizzle
    const int p0 = pixblock * PXB;
    const int t  = threadIdx.x;
    const int grp = t >> 4;      // 16-lane group, owns pixels grp and grp+16
    const int sub = t & 15;      // tap id / c4 id
    const int piA = grp, piB = grp + 16;

    // zero the weight patches (512 floats / 256 threads)
    ((float*)wpatch)[t]       = 0.0f;
    ((float*)wpatch)[t + 256] = 0.0f;

    // geometry + footprint for both pixels
    const Tap tpA = tapgeom(p0 + piA, sub, tE);
    const Tap tpB = tapgeom(p0 + piB, sub, tE);
    int bxA, byA, bxB, byB; bool pmA, pmB;
    footprint(tpA, bxA, byA, pmA);
    footprint(tpB, bxB, byB, pmB);
    if (sub == 0) {
        gbase[piA] = (byA * NSRC + bxA) * CSZ;  gmode[piA] = pmA;
        gbase[piB] = (byB * NSRC + bxB) * CSZ;  gmode[piB] = pmB;
    }
    __syncthreads();   // wpatch zeroing visible

    // scatter bilinear weights into per-pixel corner patches
    if (pmA && tpA.inb) {
        float* wp = &wpatch[piA][(tpA.y0 - byA) * 4 + (tpA.x0 - bxA)];
        atomicAdd(wp + 0, (1.0f - tpA.wx) * (1.0f - tpA.wy));
        atomicAdd(wp + 1, tpA.wx * (1.0f - tpA.wy));
        atomicAdd(wp + 4, (1.0f - tpA.wx) * tpA.wy);
        atomicAdd(wp + 5, tpA.wx * tpA.wy);
    }
    if (pmB && tpB.inb) {
        float* wp = &wpatch[piB][(tpB.y0 - byB) * 4 + (tpB.x0 - bxB)];
        atomicAdd(wp + 0, (1.0f - tpB.wx) * (1.0f - tpB.wy));
        atomicAdd(wp + 1, tpB.wx * (1.0f - tpB.wy));
        atomicAdd(wp + 4, (1.0f - tpB.wx) * tpB.wy);
        atomicAdd(wp + 5, tpB.wx * tpB.wy);
    }
    __syncthreads();

    // gather: lane sub = channels 4*sub..4*sub+3 for both pixels
    const int c4o = sub * 4;
    f32x4 accA = {0.f, 0.f, 0.f, 0.f};
    f32x4 accB = {0.f, 0.f, 0.f, 0.f};
    const int modeA = gmode[piA], modeB = gmode[piB];
    const float* __restrict__ pA = ws + gbase[piA] + c4o;
    const float* __restrict__ pB = ws + gbase[piB] + c4o;

    if (modeA & modeB) {
        // branchless: 2 bursts of 16 independent float4 loads
#pragma unroll
        for (int half = 0; half < 2; ++half) {
            f32x4 vA[8], vB[8];
            float wA[8], wB[8];
#pragma unroll
            for (int k = 0; k < 8; ++k) {
                const int cn = half * 8 + k;
                const int off = ((cn >> 2) * NSRC + (cn & 3)) * CSZ;
                vA[k] = *(const f32x4*)(pA + off);
                vB[k] = *(const f32x4*)(pB + off);
                wA[k] = wpatch[piA][cn];
                wB[k] = wpatch[piB][cn];
            }
#pragma unroll
            for (int k = 0; k < 8; ++k) {
                accA += wA[k] * vA[k];
                accB += wB[k] * vB[k];
            }
        }
    } else {
        if (modeA) {
#pragma unroll
            for (int cn = 0; cn < 16; ++cn) {
                const float w = wpatch[piA][cn];
                const f32x4 v = *(const f32x4*)
                    (pA + ((cn >> 2) * NSRC + (cn & 3)) * CSZ);
                accA += w * v;
            }
        } else {
            accA = tap_fallback(ws, tpA, c4o);
        }
        if (modeB) {
#pragma unroll
            for (int cn = 0; cn < 16; ++cn) {
                const float w = wpatch[piB][cn];
                const f32x4 v = *(const f32x4*)
                    (pB + ((cn >> 2) * NSRC + (cn & 3)) * CSZ);
                accB += w * v;
            }
        } else {
            accB = tap_fallback(ws, tpB, c4o);
        }
    }

    smemO[c4o + 0][piA] = accA.x; smemO[c4o + 1][piA] = accA.y;
    smemO[c4o + 2][piA] = accA.z; smemO[c4o + 3][piA] = accA.w;
    smemO[c4o + 0][piB] = accB.x; smemO[c4o + 1][piB] = accB.y;
    smemO[c4o + 2][piB] = accB.z; smemO[c4o + 3][piB] = accB.w;
    __syncthreads();

    // coalesced nontemporal float4 stores: 2 per thread
    {
        const int c   = t >> 2;          // 0..63
        const int px8 = (t & 3) * 8;     // 0..24
        float* op = out + (size_t)c * NPIX + p0 + px8;
        f32x4 v0, v1;
        v0.x = smemO[c][px8 + 0] * 0.0625f;
        v0.y = smemO[c][px8 + 1] * 0.0625f;
        v0.z = smemO[c][px8 + 2] * 0.0625f;
        v0.w = smemO[c][px8 + 3] * 0.0625f;
        v1.x = smemO[c][px8 + 4] * 0.0625f;
        v1.y = smemO[c][px8 + 5] * 0.0625f;
        v1.z = smemO[c][px8 + 6] * 0.0625f;
        v1.w = smemO[c][px8 + 7] * 0.0625f;
        __builtin_nontemporal_store(v0, (f32x4*)op);
        __builtin_nontemporal_store(v1, (f32x4*)(op + 4));
    }
}

extern "C" void kernel_launch(void* const* d_in, const int* in_sizes, int n_in,
                              void* d_out, int out_size, void* d_ws, size_t ws_size,
                              hipStream_t stream) {
    const float* src   = (const float*)d_in[0];
    const float* theta = (const float*)d_in[1];
    float* out = (float*)d_out;

    const size_t need = (size_t)CSZ * NSRC * NSRC * sizeof(float);  // 16.78 MB
    if (ws_size >= need) {
        float* ws = (float*)d_ws;
        transpose_kernel<<<dim3(NSRC * NSRC / 64), dim3(256), 0, stream>>>(src, ws);
        cubelens_main<<<dim3(NBLK), dim3(256), 0, stream>>>(ws, theta, out);
    } else {
        cubelens_fallback<<<dim3(NPIX / 256, 8), dim3(256), 0, stream>>>(src, theta, out);
    }
}

// Round 6
// 34.886 us; speedup vs baseline: 1.3041x; 1.3041x over previous
//
#include <hip/hip_runtime.h>

// CubeLens: radial lens deflection + bilinear gather + 4x4 avg pool.
// C=64, NS=256, NL=192, UPS=4. Output (64,192,192) fp32.
//
// R6 strategy (post-mortem of R5: LDS atomics + loading out-of-bounds
// pixels caused the regression; revert to shfl weights, keep batching):
//   k1: transpose src (64,256,256) fp32 -> ws (256,256,64) fp16.
//   k2: block = 32 px. Phase1 (16-lane group = 2 px sequentially):
//         tap geometry, footprint butterflies, per-corner weight via
//         16-step shfl accumulation; ONE plain LDS store per (px,corner)
//         (no atomics). mode: 0=all-out (33% of px -> zero work),
//         1=patch (~66%), 2=wide-span fallback (~1%).
//       Phase2 (thread = (px, 8-ch group)): 16 unconditional f16x8 corner
//         loads in 2 batches of 8 (MLP), weights broadcast from LDS.
//       Epilogue: LDS repack -> nontemporal f32x4 stores.
//       XCD swizzle: blockIdx%8 -> contiguous pixel band per XCD.

#define NSRC 256
#define NLENS 192
#define NPIX (NLENS * NLENS)     // 36864
#define CSZ  64
#define PXB  32                  // pixels per block
#define NBLK (NPIX / PXB)        // 1152, divisible by 8

typedef float    f32x4 __attribute__((ext_vector_type(4)));
typedef _Float16 f16x8 __attribute__((ext_vector_type(8)));

// ---------------- fallback (round-1 kernel, used only if ws too small) ------
__global__ __launch_bounds__(256) void cubelens_fallback(
    const float* __restrict__ src, const float* __restrict__ theta_p,
    float* __restrict__ out)
{
    const float tE = theta_p[0];
    const int pix = blockIdx.x * 256 + threadIdx.x;
    const int c0  = blockIdx.y * 8;
    const int lx  = pix % NLENS;
    const int ly  = pix / NLENS;
    float acc[8];
#pragma unroll
    for (int c = 0; c < 8; ++c) acc[c] = 0.0f;
    const float* __restrict__ srcg = src + (size_t)c0 * (NSRC * NSRC);
#pragma unroll
    for (int uy = 0; uy < 4; ++uy) {
        const float thy = ((float)(ly * 4 + uy) - 383.5f) * 0.01f;
#pragma unroll
        for (int ux = 0; ux < 4; ++ux) {
            const float thx = ((float)(lx * 4 + ux) - 383.5f) * 0.01f;
            const float r  = sqrtf(thx * thx + thy * thy) + 1e-8f;
            const float fx = (thx - (tE * thx) / r) / 0.02f + 127.5f;
            const float fy = (thy - (tE * thy) / r) / 0.02f + 127.5f;
            const bool inb = (fx >= 0.0f) & (fx <= 255.0f) &
                             (fy >= 0.0f) & (fy <= 255.0f);
            if (!inb) continue;
            int x0 = min(max((int)floorf(fx), 0), 254);
            int y0 = min(max((int)floorf(fy), 0), 254);
            const float wx = fminf(fmaxf(fx - (float)x0, 0.0f), 1.0f);
            const float wy = fminf(fmaxf(fy - (float)y0, 0.0f), 1.0f);
            const float w00 = (1.0f - wy) * (1.0f - wx);
            const float w01 = (1.0f - wy) * wx;
            const float w10 = wy * (1.0f - wx);
            const float w11 = wy * wx;
            const float* __restrict__ p = srcg + y0 * NSRC + x0;
#pragma unroll
            for (int c = 0; c < 8; ++c) {
                const float* __restrict__ pc = p + c * (NSRC * NSRC);
                acc[c] += w00 * pc[0] + w01 * pc[1]
                        + w10 * pc[NSRC] + w11 * pc[NSRC + 1];
            }
        }
    }
#pragma unroll
    for (int c = 0; c < 8; ++c)
        out[(size_t)(c0 + c) * NPIX + pix] = acc[c] * 0.0625f;
}

// ---------------- k1: transpose (c,p) fp32 -> (p,c) fp16 --------------------
__global__ __launch_bounds__(256) void transpose_kernel(
    const float* __restrict__ src, _Float16* __restrict__ ws)
{
    __shared__ float tile[CSZ][65];
    const int p0 = blockIdx.x * 64;
    const int t  = threadIdx.x;
    {
        const int crow = t >> 4;            // 0..15
        const int px4  = (t & 15) * 4;      // 0..60
#pragma unroll
        for (int i = 0; i < 4; ++i) {
            const int c = crow + 16 * i;
            const f32x4 v = __builtin_nontemporal_load(
                (const f32x4*)(src + (size_t)c * (NSRC * NSRC) + p0 + px4));
            tile[c][px4 + 0] = v.x; tile[c][px4 + 1] = v.y;
            tile[c][px4 + 2] = v.z; tile[c][px4 + 3] = v.w;
        }
    }
    __syncthreads();
    {
        const int c8 = (t & 7) * 8;         // channel group
        const int pr = t >> 3;              // 0..31
#pragma unroll
        for (int i = 0; i < 2; ++i) {
            const int p = pr + 32 * i;
            f16x8 h;
#pragma unroll
            for (int k = 0; k < 8; ++k) h[k] = (_Float16)tile[c8 + k][p];
            *(f16x8*)(ws + (size_t)(p0 + p) * CSZ + c8) = h;
        }
    }
}

// ---------------- k2: lens gather ------------------------------------------
struct Tap { int x0, y0; float wx, wy; bool inb; };

__device__ __forceinline__ Tap tapgeom(int p, int sub, float tE) {
    const int lx = p % NLENS, ly = p / NLENS;
    const float thy = ((float)(ly * 4 + (sub >> 2)) - 383.5f) * 0.01f;
    const float thx = ((float)(lx * 4 + (sub & 3))  - 383.5f) * 0.01f;
    const float r  = sqrtf(thx * thx + thy * thy) + 1e-8f;
    const float fx = (thx - (tE * thx) / r) / 0.02f + 127.5f;
    const float fy = (thy - (tE * thy) / r) / 0.02f + 127.5f;
    Tap tp;
    tp.inb = (fx >= 0.0f) & (fx <= 255.0f) & (fy >= 0.0f) & (fy <= 255.0f);
    tp.x0 = min(max((int)floorf(fx), 0), 254);
    tp.y0 = min(max((int)floorf(fy), 0), 254);
    tp.wx = fminf(fmaxf(fx - (float)tp.x0, 0.0f), 1.0f);
    tp.wy = fminf(fmaxf(fy - (float)tp.y0, 0.0f), 1.0f);
    return tp;
}

__global__ __launch_bounds__(256) void cubelens_main(
    const _Float16* __restrict__ ws,    // (256,256,64) fp16
    const float* __restrict__ theta_p,
    float* __restrict__ out)            // (64,192,192) fp32
{
    __shared__ float wpatch[PXB][16];   // per-pixel corner weights (pre /16)
    __shared__ int   gbase[PXB];
    __shared__ int   gmode[PXB];        // 0=skip 1=patch 2=fallback
    __shared__ float smemO[CSZ][PXB + 1];

    const float tE = theta_p[0];
    const int b = blockIdx.x;
    const int pixblock = (b & 7) * (NBLK / 8) + (b >> 3);   // XCD swizzle
    const int p0 = pixblock * PXB;
    const int t  = threadIdx.x;

    // ---- phase 1: geometry + per-corner weights; 16-lane group = 2 px ----
    {
        const int g = t >> 4, sub = t & 15;
#pragma unroll
        for (int h = 0; h < 2; ++h) {
            const int pi = 2 * g + h;
            const Tap tp = tapgeom(p0 + pi, sub, tE);
            const int sx0 = tp.inb ? tp.x0 : -100000;
            const int sy0 = tp.inb ? tp.y0 : -100000;
            int mnx = tp.inb ? tp.x0 :  0x0FFFFFFF;
            int mny = tp.inb ? tp.y0 :  0x0FFFFFFF;
            int mxx = tp.inb ? tp.x0 : -0x0FFFFFFF;
            int mxy = tp.inb ? tp.y0 : -0x0FFFFFFF;
#pragma unroll
            for (int off = 1; off < 16; off <<= 1) {
                mnx = min(mnx, __shfl_xor(mnx, off, 16));
                mny = min(mny, __shfl_xor(mny, off, 16));
                mxx = max(mxx, __shfl_xor(mxx, off, 16));
                mxy = max(mxy, __shfl_xor(mxy, off, 16));
            }
            const bool allout = (mnx > mxx);
            const bool pm = (mxx - mnx <= 2) && (mxy - mny <= 2);
            const int bx0 = max(min(mnx, 252), 0);
            const int by0 = max(min(mny, 252), 0);

            float myw = 0.0f;
            if (pm && !allout) {        // group-uniform
                const int cx = sub & 3, cy = sub >> 2;
#pragma unroll
                for (int j = 0; j < 16; ++j) {
                    const int   tx0 = __shfl(sx0, j, 16);
                    const int   ty0 = __shfl(sy0, j, 16);
                    const float twx = __shfl(tp.wx, j, 16);
                    const float twy = __shfl(tp.wy, j, 16);
                    const int ax = cx - (tx0 - bx0);
                    const int ay = cy - (ty0 - by0);
                    if (((unsigned)ax <= 1u) & ((unsigned)ay <= 1u))
                        myw += (ax ? twx : 1.0f - twx) * (ay ? twy : 1.0f - twy);
                }
            }
            wpatch[pi][sub] = myw * 0.0625f;
            if (sub == 0) {
                gbase[pi] = (by0 * NSRC + bx0) * CSZ;
                gmode[pi] = allout ? 0 : (pm ? 1 : 2);
            }
        }
    }
    __syncthreads();

    // ---- phase 2: gather. thread = (pixel, 8-channel group) ----
    {
        const int pi = t >> 3, c8 = t & 7;
        const int mode = gmode[pi];
        float acc[8];
#pragma unroll
        for (int e = 0; e < 8; ++e) acc[e] = 0.0f;

        if (mode == 1) {
            const _Float16* __restrict__ base = ws + gbase[pi] + c8 * 8;
#pragma unroll
            for (int half = 0; half < 2; ++half) {
                f16x8 v[8];
                float w[8];
#pragma unroll
                for (int k = 0; k < 8; ++k) {
                    const int cn = half * 8 + k;
                    v[k] = *(const f16x8*)(base + ((cn >> 2) * NSRC + (cn & 3)) * CSZ);
                    w[k] = wpatch[pi][cn];
                }
#pragma unroll
                for (int k = 0; k < 8; ++k)
#pragma unroll
                    for (int e = 0; e < 8; ++e)
                        acc[e] += w[k] * (float)v[k][e];
            }
        } else if (mode == 2) {
            // rare wide-span pixel: recompute taps serially
            for (int tap = 0; tap < 16; ++tap) {
                const Tap tp = tapgeom(p0 + pi, tap, tE);
                if (tp.inb) {
                    const _Float16* __restrict__ pp =
                        ws + (tp.y0 * NSRC + tp.x0) * CSZ + c8 * 8;
                    const f16x8 v00 = *(const f16x8*)(pp);
                    const f16x8 v01 = *(const f16x8*)(pp + CSZ);
                    const f16x8 v10 = *(const f16x8*)(pp + NSRC * CSZ);
                    const f16x8 v11 = *(const f16x8*)(pp + NSRC * CSZ + CSZ);
                    const float w00 = (1.0f - tp.wy) * (1.0f - tp.wx);
                    const float w01 = (1.0f - tp.wy) * tp.wx;
                    const float w10 = tp.wy * (1.0f - tp.wx);
                    const float w11 = tp.wy * tp.wx;
#pragma unroll
                    for (int e = 0; e < 8; ++e)
                        acc[e] += w00 * (float)v00[e] + w01 * (float)v01[e]
                                + w10 * (float)v10[e] + w11 * (float)v11[e];
                }
            }
#pragma unroll
            for (int e = 0; e < 8; ++e) acc[e] *= 0.0625f;
        }

#pragma unroll
        for (int e = 0; e < 8; ++e) smemO[c8 * 8 + e][pi] = acc[e];
    }
    __syncthreads();

    // ---- epilogue: coalesced nontemporal f32x4 stores ----
    {
        const int c   = t >> 2;          // 0..63
        const int px8 = (t & 3) * 8;     // 0,8,16,24
        float* op = out + (size_t)c * NPIX + p0 + px8;
        f32x4 v0, v1;
        v0.x = smemO[c][px8 + 0]; v0.y = smemO[c][px8 + 1];
        v0.z = smemO[c][px8 + 2]; v0.w = smemO[c][px8 + 3];
        v1.x = smemO[c][px8 + 4]; v1.y = smemO[c][px8 + 5];
        v1.z = smemO[c][px8 + 6]; v1.w = smemO[c][px8 + 7];
        __builtin_nontemporal_store(v0, (f32x4*)op);
        __builtin_nontemporal_store(v1, (f32x4*)(op + 4));
    }
}

extern "C" void kernel_launch(void* const* d_in, const int* in_sizes, int n_in,
                              void* d_out, int out_size, void* d_ws, size_t ws_size,
                              hipStream_t stream) {
    const float* src   = (const float*)d_in[0];
    const float* theta = (const float*)d_in[1];
    float* out = (float*)d_out;

    const size_t need = (size_t)CSZ * NSRC * NSRC * sizeof(_Float16);  // 8.4 MB
    if (ws_size >= need) {
        _Float16* ws = (_Float16*)d_ws;
        transpose_kernel<<<dim3(NSRC * NSRC / 64), dim3(256), 0, stream>>>(src, ws);
        cubelens_main<<<dim3(NBLK), dim3(256), 0, stream>>>(ws, theta, out);
    } else {
        cubelens_fallback<<<dim3(NPIX / 256, 8), dim3(256), 0, stream>>>(src, theta, out);
    }
}

// Round 8
// 31.649 us; speedup vs baseline: 1.4375x; 1.1023x over previous
//
#include <hip/hip_runtime.h>

// CubeLens: radial lens deflection + bilinear gather + 4x4 avg pool.
// C=64, NS=256, NL=192, UPS=4. Output (64,192,192) fp32.
//
// R8 = R7 with phase-1B coverage bug fixed (was computing corner weights
// for only 16 of 32 pixels -> uninitialized wpatch -> absmax 8).
//
//   k1: fp32 -> fp16 channel-last transpose.
//   k2: Phase 1A (lane=(2px group, tap)): geometry; min + viol via bperm
//       butterflies; store {dx,dy,wx,wy} tap record (ds_write_b128).
//       Phase 1B (lane=(px, corner), 2 px per lane): 16 batched
//       ds_read_b128 + exact float-compare bilinear select. No serial
//       shfl round-trip chains.
//       Phase 2 (lane=(px, c8)): mode-gated 16x f16x8 batched corner
//       loads (2 batches of 8), weights broadcast from LDS.
//       Epilogue: LDS repack -> nontemporal f32x4 stores.
//       XCD swizzle: blockIdx%8 -> contiguous pixel band per XCD.

#define NSRC 256
#define NLENS 192
#define NPIX (NLENS * NLENS)     // 36864
#define CSZ  64
#define PXB  32                  // pixels per block
#define NBLK (NPIX / PXB)        // 1152, divisible by 8

typedef float    f32x4 __attribute__((ext_vector_type(4)));
typedef _Float16 f16x8 __attribute__((ext_vector_type(8)));

// ---------------- fallback (round-1 kernel, used only if ws too small) ------
__global__ __launch_bounds__(256) void cubelens_fallback(
    const float* __restrict__ src, const float* __restrict__ theta_p,
    float* __restrict__ out)
{
    const float tE = theta_p[0];
    const int pix = blockIdx.x * 256 + threadIdx.x;
    const int c0  = blockIdx.y * 8;
    const int lx  = pix % NLENS;
    const int ly  = pix / NLENS;
    float acc[8];
#pragma unroll
    for (int c = 0; c < 8; ++c) acc[c] = 0.0f;
    const float* __restrict__ srcg = src + (size_t)c0 * (NSRC * NSRC);
#pragma unroll
    for (int uy = 0; uy < 4; ++uy) {
        const float thy = ((float)(ly * 4 + uy) - 383.5f) * 0.01f;
#pragma unroll
        for (int ux = 0; ux < 4; ++ux) {
            const float thx = ((float)(lx * 4 + ux) - 383.5f) * 0.01f;
            const float r  = sqrtf(thx * thx + thy * thy) + 1e-8f;
            const float fx = (thx - (tE * thx) / r) / 0.02f + 127.5f;
            const float fy = (thy - (tE * thy) / r) / 0.02f + 127.5f;
            const bool inb = (fx >= 0.0f) & (fx <= 255.0f) &
                             (fy >= 0.0f) & (fy <= 255.0f);
            if (!inb) continue;
            int x0 = min(max((int)floorf(fx), 0), 254);
            int y0 = min(max((int)floorf(fy), 0), 254);
            const float wx = fminf(fmaxf(fx - (float)x0, 0.0f), 1.0f);
            const float wy = fminf(fmaxf(fy - (float)y0, 0.0f), 1.0f);
            const float w00 = (1.0f - wy) * (1.0f - wx);
            const float w01 = (1.0f - wy) * wx;
            const float w10 = wy * (1.0f - wx);
            const float w11 = wy * wx;
            const float* __restrict__ p = srcg + y0 * NSRC + x0;
#pragma unroll
            for (int c = 0; c < 8; ++c) {
                const float* __restrict__ pc = p + c * (NSRC * NSRC);
                acc[c] += w00 * pc[0] + w01 * pc[1]
                        + w10 * pc[NSRC] + w11 * pc[NSRC + 1];
            }
        }
    }
#pragma unroll
    for (int c = 0; c < 8; ++c)
        out[(size_t)(c0 + c) * NPIX + pix] = acc[c] * 0.0625f;
}

// ---------------- k1: transpose (c,p) fp32 -> (p,c) fp16 --------------------
__global__ __launch_bounds__(256) void transpose_kernel(
    const float* __restrict__ src, _Float16* __restrict__ ws)
{
    __shared__ float tile[CSZ][65];
    const int p0 = blockIdx.x * 64;
    const int t  = threadIdx.x;
    {
        const int crow = t >> 4;            // 0..15
        const int px4  = (t & 15) * 4;      // 0..60
#pragma unroll
        for (int i = 0; i < 4; ++i) {
            const int c = crow + 16 * i;
            const f32x4 v = __builtin_nontemporal_load(
                (const f32x4*)(src + (size_t)c * (NSRC * NSRC) + p0 + px4));
            tile[c][px4 + 0] = v.x; tile[c][px4 + 1] = v.y;
            tile[c][px4 + 2] = v.z; tile[c][px4 + 3] = v.w;
        }
    }
    __syncthreads();
    {
        const int c8 = (t & 7) * 8;         // channel group
        const int pr = t >> 3;              // 0..31
#pragma unroll
        for (int i = 0; i < 2; ++i) {
            const int p = pr + 32 * i;
            f16x8 h;
#pragma unroll
            for (int k = 0; k < 8; ++k) h[k] = (_Float16)tile[c8 + k][p];
            *(f16x8*)(ws + (size_t)(p0 + p) * CSZ + c8) = h;
        }
    }
}

// ---------------- k2: lens gather ------------------------------------------
struct Tap { int x0, y0; float wx, wy; bool inb; };

__device__ __forceinline__ Tap tapgeom(int p, int sub, float tE) {
    const int lx = p % NLENS, ly = p / NLENS;
    const float thy = ((float)(ly * 4 + (sub >> 2)) - 383.5f) * 0.01f;
    const float thx = ((float)(lx * 4 + (sub & 3))  - 383.5f) * 0.01f;
    const float r  = sqrtf(thx * thx + thy * thy) + 1e-8f;
    const float fx = (thx - (tE * thx) / r) / 0.02f + 127.5f;
    const float fy = (thy - (tE * thy) / r) / 0.02f + 127.5f;
    Tap tp;
    tp.inb = (fx >= 0.0f) & (fx <= 255.0f) & (fy >= 0.0f) & (fy <= 255.0f);
    tp.x0 = min(max((int)floorf(fx), 0), 254);
    tp.y0 = min(max((int)floorf(fy), 0), 254);
    tp.wx = fminf(fmaxf(fx - (float)tp.x0, 0.0f), 1.0f);
    tp.wy = fminf(fmaxf(fy - (float)tp.y0, 0.0f), 1.0f);
    return tp;
}

__global__ __launch_bounds__(256) void cubelens_main(
    const _Float16* __restrict__ ws,    // (256,256,64) fp16
    const float* __restrict__ theta_p,
    float* __restrict__ out)            // (64,192,192) fp32
{
    __shared__ f32x4 Btap[PXB][16];     // per-tap {dx, dy, wx, wy}
    __shared__ float wpatch[PXB][16];   // per-pixel corner weights (pre /16)
    __shared__ int   gbase[PXB];
    __shared__ int   gmode[PXB];        // 0=skip 1=patch 2=fallback
    __shared__ float smemO[CSZ][PXB + 1];

    const float tE = theta_p[0];
    const int b = blockIdx.x;
    const int pixblock = (b & 7) * (NBLK / 8) + (b >> 3);   // XCD swizzle
    const int p0 = pixblock * PXB;
    const int t  = threadIdx.x;

    // ---- phase 1A: tap geometry + patch base; lanes = (group, tap) ----
    {
        const int g = t >> 4, sub = t & 15;
#pragma unroll
        for (int h = 0; h < 2; ++h) {
            const int pi = 2 * g + h;
            const Tap tp = tapgeom(p0 + pi, sub, tE);
            const float x0f = (float)tp.x0, y0f = (float)tp.y0;
            float mnx = tp.inb ? x0f : 1e9f;
            float mny = tp.inb ? y0f : 1e9f;
#pragma unroll
            for (int off = 1; off < 16; off <<= 1) {
                mnx = fminf(mnx, __shfl_xor(mnx, off, 16));
                mny = fminf(mny, __shfl_xor(mny, off, 16));
            }
            const bool allout = (mnx > 5e8f);
            // span violation vs raw mins
            int viol = (tp.inb & ((x0f > mnx + 2.0f) | (y0f > mny + 2.0f))) ? 1 : 0;
#pragma unroll
            for (int off = 1; off < 16; off <<= 1)
                viol |= __shfl_xor(viol, off, 16);
            // clamped patch base
            const float bxc = fminf(mnx, 252.0f);
            const float byc = fminf(mny, 252.0f);
            f32x4 rec;
            rec.x = tp.inb ? (x0f - bxc) : -1000.0f;
            rec.y = tp.inb ? (y0f - byc) : -1000.0f;
            rec.z = tp.wx;
            rec.w = tp.wy;
            Btap[pi][sub] = rec;
            if (sub == 0) {
                gbase[pi] = (((int)byc) * NSRC + (int)bxc) * CSZ;
                gmode[pi] = allout ? 0 : (viol ? 2 : 1);
            }
        }
    }
    __syncthreads();

    // ---- phase 1B: corner weights; lanes = (pixel, corner); 2 px/lane ----
    {
        const int sub = t & 15;
        const float cxf = (float)(sub & 3), cyf = (float)(sub >> 2);
#pragma unroll
        for (int h = 0; h < 2; ++h) {
            const int pi = (t >> 4) + 16 * h;     // covers all 32 pixels
            float myw = 0.0f;
#pragma unroll
            for (int j = 0; j < 16; ++j) {
                const f32x4 r = Btap[pi][j];
                const float tx = cxf - r.x;        // in {0,1} iff corner hit
                const float ty = cyf - r.y;
                const float wxp = (tx == 0.0f) ? (1.0f - r.z)
                                : ((tx == 1.0f) ? r.z : 0.0f);
                const float wyp = (ty == 0.0f) ? (1.0f - r.w)
                                : ((ty == 1.0f) ? r.w : 0.0f);
                myw += wxp * wyp;
            }
            wpatch[pi][sub] = myw * 0.0625f;
        }
    }
    __syncthreads();

    // ---- phase 2: gather. thread = (pixel, 8-channel group) ----
    {
        const int pi = t >> 3, c8 = t & 7;
        const int mode = gmode[pi];
        float acc[8];
#pragma unroll
        for (int e = 0; e < 8; ++e) acc[e] = 0.0f;

        if (mode == 1) {
            const _Float16* __restrict__ base = ws + gbase[pi] + c8 * 8;
#pragma unroll
            for (int half = 0; half < 2; ++half) {
                f16x8 v[8];
                float w[8];
#pragma unroll
                for (int k = 0; k < 8; ++k) {
                    const int cn = half * 8 + k;
                    v[k] = *(const f16x8*)(base + ((cn >> 2) * NSRC + (cn & 3)) * CSZ);
                    w[k] = wpatch[pi][cn];
                }
#pragma unroll
                for (int k = 0; k < 8; ++k)
#pragma unroll
                    for (int e = 0; e < 8; ++e)
                        acc[e] += w[k] * (float)v[k][e];   // v_fma_mix_f32
            }
        } else if (mode == 2) {
            // rare wide-span pixel: recompute taps serially
            for (int tap = 0; tap < 16; ++tap) {
                const Tap tp = tapgeom(p0 + pi, tap, tE);
                if (tp.inb) {
                    const _Float16* __restrict__ pp =
                        ws + (tp.y0 * NSRC + tp.x0) * CSZ + c8 * 8;
                    const f16x8 v00 = *(const f16x8*)(pp);
                    const f16x8 v01 = *(const f16x8*)(pp + CSZ);
                    const f16x8 v10 = *(const f16x8*)(pp + NSRC * CSZ);
                    const f16x8 v11 = *(const f16x8*)(pp + NSRC * CSZ + CSZ);
                    const float w00 = (1.0f - tp.wy) * (1.0f - tp.wx);
                    const float w01 = (1.0f - tp.wy) * tp.wx;
                    const float w10 = tp.wy * (1.0f - tp.wx);
                    const float w11 = tp.wy * tp.wx;
#pragma unroll
                    for (int e = 0; e < 8; ++e)
                        acc[e] += w00 * (float)v00[e] + w01 * (float)v01[e]
                                + w10 * (float)v10[e] + w11 * (float)v11[e];
                }
            }
#pragma unroll
            for (int e = 0; e < 8; ++e) acc[e] *= 0.0625f;
        }

#pragma unroll
        for (int e = 0; e < 8; ++e) smemO[c8 * 8 + e][pi] = acc[e];
    }
    __syncthreads();

    // ---- epilogue: coalesced nontemporal f32x4 stores ----
    {
        const int c   = t >> 2;          // 0..63
        const int px8 = (t & 3) * 8;     // 0,8,16,24
        float* op = out + (size_t)c * NPIX + p0 + px8;
        f32x4 v0, v1;
        v0.x = smemO[c][px8 + 0]; v0.y = smemO[c][px8 + 1];
        v0.z = smemO[c][px8 + 2]; v0.w = smemO[c][px8 + 3];
        v1.x = smemO[c][px8 + 4]; v1.y = smemO[c][px8 + 5];
        v1.z = smemO[c][px8 + 6]; v1.w = smemO[c][px8 + 7];
        __builtin_nontemporal_store(v0, (f32x4*)op);
        __builtin_nontemporal_store(v1, (f32x4*)(op + 4));
    }
}

extern "C" void kernel_launch(void* const* d_in, const int* in_sizes, int n_in,
                              void* d_out, int out_size, void* d_ws, size_t ws_size,
                              hipStream_t stream) {
    const float* src   = (const float*)d_in[0];
    const float* theta = (const float*)d_in[1];
    float* out = (float*)d_out;

    const size_t need = (size_t)CSZ * NSRC * NSRC * sizeof(_Float16);  // 8.4 MB
    if (ws_size >= need) {
        _Float16* ws = (_Float16*)d_ws;
        transpose_kernel<<<dim3(NSRC * NSRC / 64), dim3(256), 0, stream>>>(src, ws);
        cubelens_main<<<dim3(NBLK), dim3(256), 0, stream>>>(ws, theta, out);
    } else {
        cubelens_fallback<<<dim3(NPIX / 256, 8), dim3(256), 0, stream>>>(src, theta, out);
    }
}